// Round 5
// baseline (121.416 us; speedup 1.0000x reference)
//
#include <hip/hip_runtime.h>
#include <utility>

// ---------------------------------------------------------------------------
// Compile-time port of the reference's _su2_cg / _q / wigner_3j.
// All Wigner-3j coefficients are computed by the C++ compiler at constexpr
// time and baked into the kernel as immediates (sparse nonzero table).
// ---------------------------------------------------------------------------
namespace w3j {

constexpr int NP = 15;
// PATHS = (i_in1, i_in2, i_out), same order as reference (weight indexing!)
constexpr int P1[NP] = {0,0,0,1,1,1,1,1,1,2,2,2,2,2,2};
constexpr int P2[NP] = {0,1,2,0,1,1,1,2,2,0,1,1,2,2,2};
constexpr int P3[NP] = {0,1,2,1,0,1,2,1,2,2,1,2,0,1,2};
constexpr int BASE[3] = {0,1,4};   // offset of l-block within the 9-wide irrep vector

constexpr double cfact(int n){ double r = 1.0; for (int i = 2; i <= n; ++i) r *= i; return r; }
constexpr double csqrt(double x){
  double g = x > 1.0 ? x : 1.0;
  for (int i = 0; i < 64; ++i){ double ng = 0.5*(g + x/g); if (ng == g) break; g = ng; }
  return g;
}
constexpr double neg1pow(int n){ return (n & 1) ? -1.0 : 1.0; }
constexpr int imax3(int a,int b,int c){ int m = a > b ? a : b; return m > c ? m : c; }
constexpr int imin3(int a,int b,int c){ int m = a < b ? a : b; return m < c ? m : c; }

constexpr double su2_cg(int j1,int j2,int j3,int m1,int m2,int m3){
  if (m3 != m1 + m2) return 0.0;
  int vmin = imax3(-j1 + j2 + m3, -j1 + m1, 0);
  int vmax = imin3(j2 + j3 + m1, j3 - j1 + j2, j3 + m3);
  double C = csqrt((2*j3 + 1) * cfact(j3 + j1 - j2) * cfact(j3 - j1 + j2) * cfact(j1 + j2 - j3)
                   * cfact(j3 + m3) * cfact(j3 - m3)
                   / (cfact(j1 + j2 + j3 + 1) * cfact(j1 - m1) * cfact(j1 + m1)
                      * cfact(j2 - m2) * cfact(j2 + m2)));
  double S = 0.0;
  for (int v = vmin; v <= vmax; ++v)
    S += neg1pow(v + j2 + m2) * cfact(j2 + j3 + m1 - v) * cfact(j1 - m1 + v)
         / (cfact(v) * cfact(j3 - j1 + j2 - v) * cfact(j3 + m3 - v) * cfact(v + j1 - j2 - m3));
  return C * S;
}

struct cplx { double re, im; };
constexpr cplx cmul(cplx a, cplx b){ return { a.re*b.re - a.im*b.im, a.re*b.im + a.im*b.re }; }
constexpr cplx cadd(cplx a, cplx b){ return { a.re + b.re, a.im + b.im }; }

struct QM { cplx q[5][5]; };
constexpr QM qmat(int l){
  QM Q{};
  const double is2 = 1.0 / csqrt(2.0);
  for (int m = -l; m < 0; ++m){
    Q.q[l+m][l-m] = cplx{ is2, 0.0 };
    Q.q[l+m][l+m] = cplx{ 0.0, -is2 };
  }
  Q.q[l][l] = cplx{ 1.0, 0.0 };
  for (int m = 1; m <= l; ++m){
    double s = neg1pow(m);
    Q.q[l+m][l+m] = cplx{ s*is2, 0.0 };
    Q.q[l+m][l-m] = cplx{ 0.0, s*is2 };
  }
  cplx f{1.0, 0.0};
  for (int t = 0; t < l; ++t) f = cmul(f, cplx{0.0, -1.0});   // (-i)^l
  for (int a = 0; a < 2*l+1; ++a) for (int b = 0; b < 2*l+1; ++b) Q.q[a][b] = cmul(Q.q[a][b], f);
  return Q;
}

struct W3 { double w[5][5][5]; };
constexpr W3 wig(int l1,int l2,int l3){
  const int d1 = 2*l1+1, d2 = 2*l2+1, d3 = 2*l3+1;
  double C[5][5][5] = {};
  for (int a = 0; a < d1; ++a) for (int b = 0; b < d2; ++b) for (int c = 0; c < d3; ++c)
    C[a][b][c] = su2_cg(l1, l2, l3, a - l1, b - l2, c - l3);
  const QM q1 = qmat(l1), q2 = qmat(l2), q3 = qmat(l3);
  cplx T1[5][5][5] = {};
  for (int j = 0; j < d1; ++j) for (int k = 0; k < d2; ++k) for (int n = 0; n < d3; ++n){
    cplx s{0,0};
    for (int i = 0; i < d1; ++i) s = cadd(s, cmul(q1.q[i][j], cplx{ C[i][k][n], 0.0 }));
    T1[j][k][n] = s;
  }
  cplx T2[5][5][5] = {};
  for (int j = 0; j < d1; ++j) for (int l = 0; l < d2; ++l) for (int n = 0; n < d3; ++n){
    cplx s{0,0};
    for (int k = 0; k < d2; ++k) s = cadd(s, cmul(q2.q[k][l], T1[j][k][n]));
    T2[j][l][n] = s;
  }
  W3 W{};
  for (int j = 0; j < d1; ++j) for (int l = 0; l < d2; ++l) for (int m = 0; m < d3; ++m){
    cplx s{0,0};
    for (int n = 0; n < d3; ++n)
      s = cadd(s, cmul(cplx{ q3.q[n][m].re, -q3.q[n][m].im }, T2[j][l][n]));
    W.w[j][l][m] = s.re;
  }
  return W;
}

constexpr W3 W_00 = wig(0,0,0);
constexpr W3 W_01 = wig(0,1,1);
constexpr W3 W_02 = wig(0,2,2);
constexpr W3 W_03 = wig(1,0,1);
constexpr W3 W_04 = wig(1,1,0);
constexpr W3 W_05 = wig(1,1,1);
constexpr W3 W_06 = wig(1,1,2);
constexpr W3 W_07 = wig(1,2,1);
constexpr W3 W_08 = wig(1,2,2);
constexpr W3 W_09 = wig(2,0,2);
constexpr W3 W_10 = wig(2,1,1);
constexpr W3 W_11 = wig(2,1,2);
constexpr W3 W_12 = wig(2,2,0);
constexpr W3 W_13 = wig(2,2,1);
constexpr W3 W_14 = wig(2,2,2);

struct Entry { int p, gi, gj, gk; float v; };
struct Table { Entry e[615]; int n; };
constexpr Table build(){
  const W3 WS[NP] = { W_00,W_01,W_02,W_03,W_04,W_05,W_06,W_07,
                      W_08,W_09,W_10,W_11,W_12,W_13,W_14 };
  Table t{};
  for (int p = 0; p < NP; ++p){
    const int l1 = P1[p], l2 = P2[p], l3 = P3[p];
    for (int i = 0; i < 2*l1+1; ++i)
      for (int j = 0; j < 2*l2+1; ++j)
        for (int k = 0; k < 2*l3+1; ++k){
          double v = WS[p].w[i][j][k];
          if (v > 1e-12 || v < -1e-12){
            t.e[t.n] = Entry{ p, BASE[l1] + i, BASE[l2] + j, BASE[l3] + k, (float)v };
            ++t.n;
          }
        }
  }
  return t;
}
constexpr Table TBL = build();
constexpr int NNZ = TBL.n;

} // namespace w3j

// ---------------------------------------------------------------------------
// Unrolled sparse contraction (all indices/coefficients compile-time const).
// ---------------------------------------------------------------------------
template<int E>
__device__ __forceinline__ void apply_one(const float (&xx)[9], const float (&yv)[9],
                                          const float (&wp)[w3j::NP], float (&oo)[9]){
  constexpr w3j::Entry en = w3j::TBL.e[E];
  oo[en.gk] = fmaf(wp[en.p] * xx[en.gi] * en.v, yv[en.gj], oo[en.gk]);
}

template<int... Es>
__device__ __forceinline__ void apply_all(std::integer_sequence<int, Es...>,
                                          const float (&xx)[9], const float (&yv)[9],
                                          const float (&wp)[w3j::NP], float (&oo)[9]){
  (apply_one<Es>(xx, yv, wp, oo), ...);
}

// ---------------------------------------------------------------------------
// Register-only, LDS-free design.
//   - typedefs with aligned(4) let hipcc emit global_load_dwordx3/x4 at 4 B
//     alignment (gfx950 supports unaligned global access); worst case the
//     compiler splits into dwords (== R0 behavior, no regression).
//   - 4 rows per WAVE: row base is wave-uniform (readfirstlane) so y-loads
//     become s_load on the scalar pipe (SGPRs, no VMEM slots), and the 16
//     x-loads per lane issue back-to-back for deep VMEM pipelining.
//   - per row per lane: 4 VMEM loads (dword, x3, x4, dword) + 4 VMEM stores.
//     Zero DS ops, zero barriers.
// ---------------------------------------------------------------------------
typedef float f3u __attribute__((ext_vector_type(3), aligned(4)));
typedef float f4u __attribute__((ext_vector_type(4), aligned(4)));

constexpr int WR = 4;                       // rows per wave
constexpr int RF = 576;                     // floats per row

__global__ __launch_bounds__(256)
void tp_rescale_kernel(const float* __restrict__ x, const float* __restrict__ y,
                       const float* __restrict__ w, const float* __restrict__ b,
                       float* __restrict__ out)
{
  const int t    = threadIdx.x;
  const int u    = t & 63;                                   // lane = channel
  const int wv   = __builtin_amdgcn_readfirstlane(t >> 6);   // SGPR wave id
  const long rowbase = ((long)blockIdx.x * 4 + wv) * WR;     // wave-uniform

  // ---- load all 4 rows' x slices (16 VMEM loads in flight) ----
  float xx[WR][9];
  #pragma unroll
  for (int r = 0; r < WR; ++r) {
    const float* xr = x + (rowbase + r) * RF;
    xx[r][0] = xr[u];                                        // dword
    f3u a = *(const f3u*)(xr + 64 + 3 * u);                  // dwordx3
    f4u c = *(const f4u*)(xr + 256 + 5 * u);                 // dwordx4
    float e = xr[256 + 5 * u + 4];                           // dword
    xx[r][1] = a[0]; xx[r][2] = a[1]; xx[r][3] = a[2];
    xx[r][4] = c[0]; xx[r][5] = c[1]; xx[r][6] = c[2]; xx[r][7] = c[3];
    xx[r][8] = e;
  }

  // ---- y: wave-uniform addresses -> scalar (SMEM) loads into SGPRs ----
  float yv[WR][9];
  #pragma unroll
  for (int r = 0; r < WR; ++r)
    #pragma unroll
    for (int j = 0; j < 9; ++j) yv[r][j] = y[(rowbase + r) * 9 + j];

  // ---- per-lane weights/bias (coalesced dword broadcasts, L1-resident) ----
  float wp[w3j::NP];
  #pragma unroll
  for (int p = 0; p < w3j::NP; ++p) wp[p] = w[p * 64 + u];
  const float bu = b[u];

  // ---- compute + store, row by row (stores overlap next row's compute) ----
  #pragma unroll
  for (int r = 0; r < WR; ++r) {
    float oo[9];
    #pragma unroll
    for (int k = 0; k < 9; ++k) oo[k] = 0.0f;

    apply_all(std::make_integer_sequence<int, w3j::NNZ>{}, xx[r], yv[r], wp, oo);

    float* orow = out + (rowbase + r) * RF;
    orow[u] = oo[0] + bu;                                    // bias on 0e slice
    f3u s1; s1[0] = oo[1]; s1[1] = oo[2]; s1[2] = oo[3];
    *(f3u*)(orow + 64 + 3 * u) = s1;                         // dwordx3
    f4u s2; s2[0] = oo[4]; s2[1] = oo[5]; s2[2] = oo[6]; s2[3] = oo[7];
    *(f4u*)(orow + 256 + 5 * u) = s2;                        // dwordx4
    orow[256 + 5 * u + 4] = oo[8];                           // dword
  }
}

extern "C" void kernel_launch(void* const* d_in, const int* in_sizes, int n_in,
                              void* d_out, int out_size, void* d_ws, size_t ws_size,
                              hipStream_t stream) {
  const float* x = (const float*)d_in[0];
  const float* y = (const float*)d_in[1];
  const float* w = (const float*)d_in[2];
  const float* b = (const float*)d_in[3];
  float* out = (float*)d_out;

  const int nrows = in_sizes[0] / 576;      // 131072, divisible by 16
  const int blocks = nrows / (4 * WR);      // 4 waves/block * 4 rows/wave = 8192

  hipLaunchKernelGGL(tp_rescale_kernel, dim3(blocks), dim3(256), 0, stream,
                     x, y, w, b, out);
}

// Round 7
// 106.054 us; speedup vs baseline: 1.1449x; 1.1449x over previous
//
#include <hip/hip_runtime.h>
#include <utility>

// ---------------------------------------------------------------------------
// Compile-time port of the reference's _su2_cg / _q / wigner_3j.
// All Wigner-3j coefficients are computed by the C++ compiler at constexpr
// time and baked into the kernel as immediates (sparse nonzero table).
// ---------------------------------------------------------------------------
namespace w3j {

constexpr int NP = 15;
// PATHS = (i_in1, i_in2, i_out), same order as reference (weight indexing!)
constexpr int P1[NP] = {0,0,0,1,1,1,1,1,1,2,2,2,2,2,2};
constexpr int P2[NP] = {0,1,2,0,1,1,1,2,2,0,1,1,2,2,2};
constexpr int P3[NP] = {0,1,2,1,0,1,2,1,2,2,1,2,0,1,2};
constexpr int BASE[3] = {0,1,4};   // offset of l-block within the 9-wide irrep vector

constexpr double cfact(int n){ double r = 1.0; for (int i = 2; i <= n; ++i) r *= i; return r; }
constexpr double csqrt(double x){
  double g = x > 1.0 ? x : 1.0;
  for (int i = 0; i < 64; ++i){ double ng = 0.5*(g + x/g); if (ng == g) break; g = ng; }
  return g;
}
constexpr double neg1pow(int n){ return (n & 1) ? -1.0 : 1.0; }
constexpr int imax3(int a,int b,int c){ int m = a > b ? a : b; return m > c ? m : c; }
constexpr int imin3(int a,int b,int c){ int m = a < b ? a : b; return m < c ? m : c; }

constexpr double su2_cg(int j1,int j2,int j3,int m1,int m2,int m3){
  if (m3 != m1 + m2) return 0.0;
  int vmin = imax3(-j1 + j2 + m3, -j1 + m1, 0);
  int vmax = imin3(j2 + j3 + m1, j3 - j1 + j2, j3 + m3);
  double C = csqrt((2*j3 + 1) * cfact(j3 + j1 - j2) * cfact(j3 - j1 + j2) * cfact(j1 + j2 - j3)
                   * cfact(j3 + m3) * cfact(j3 - m3)
                   / (cfact(j1 + j2 + j3 + 1) * cfact(j1 - m1) * cfact(j1 + m1)
                      * cfact(j2 - m2) * cfact(j2 + m2)));
  double S = 0.0;
  for (int v = vmin; v <= vmax; ++v)
    S += neg1pow(v + j2 + m2) * cfact(j2 + j3 + m1 - v) * cfact(j1 - m1 + v)
         / (cfact(v) * cfact(j3 - j1 + j2 - v) * cfact(j3 + m3 - v) * cfact(v + j1 - j2 - m3));
  return C * S;
}

struct cplx { double re, im; };
constexpr cplx cmul(cplx a, cplx b){ return { a.re*b.re - a.im*b.im, a.re*b.im + a.im*b.re }; }
constexpr cplx cadd(cplx a, cplx b){ return { a.re + b.re, a.im + b.im }; }

struct QM { cplx q[5][5]; };
constexpr QM qmat(int l){
  QM Q{};
  const double is2 = 1.0 / csqrt(2.0);
  for (int m = -l; m < 0; ++m){
    Q.q[l+m][l-m] = cplx{ is2, 0.0 };
    Q.q[l+m][l+m] = cplx{ 0.0, -is2 };
  }
  Q.q[l][l] = cplx{ 1.0, 0.0 };
  for (int m = 1; m <= l; ++m){
    double s = neg1pow(m);
    Q.q[l+m][l+m] = cplx{ s*is2, 0.0 };
    Q.q[l+m][l-m] = cplx{ 0.0, s*is2 };
  }
  cplx f{1.0, 0.0};
  for (int t = 0; t < l; ++t) f = cmul(f, cplx{0.0, -1.0});   // (-i)^l
  for (int a = 0; a < 2*l+1; ++a) for (int b = 0; b < 2*l+1; ++b) Q.q[a][b] = cmul(Q.q[a][b], f);
  return Q;
}

struct W3 { double w[5][5][5]; };
constexpr W3 wig(int l1,int l2,int l3){
  const int d1 = 2*l1+1, d2 = 2*l2+1, d3 = 2*l3+1;
  double C[5][5][5] = {};
  for (int a = 0; a < d1; ++a) for (int b = 0; b < d2; ++b) for (int c = 0; c < d3; ++c)
    C[a][b][c] = su2_cg(l1, l2, l3, a - l1, b - l2, c - l3);
  const QM q1 = qmat(l1), q2 = qmat(l2), q3 = qmat(l3);
  cplx T1[5][5][5] = {};
  for (int j = 0; j < d1; ++j) for (int k = 0; k < d2; ++k) for (int n = 0; n < d3; ++n){
    cplx s{0,0};
    for (int i = 0; i < d1; ++i) s = cadd(s, cmul(q1.q[i][j], cplx{ C[i][k][n], 0.0 }));
    T1[j][k][n] = s;
  }
  cplx T2[5][5][5] = {};
  for (int j = 0; j < d1; ++j) for (int l = 0; l < d2; ++l) for (int n = 0; n < d3; ++n){
    cplx s{0,0};
    for (int k = 0; k < d2; ++k) s = cadd(s, cmul(q2.q[k][l], T1[j][k][n]));
    T2[j][l][n] = s;
  }
  W3 W{};
  for (int j = 0; j < d1; ++j) for (int l = 0; l < d2; ++l) for (int m = 0; m < d3; ++m){
    cplx s{0,0};
    for (int n = 0; n < d3; ++n)
      s = cadd(s, cmul(cplx{ q3.q[n][m].re, -q3.q[n][m].im }, T2[j][l][n]));
    W.w[j][l][m] = s.re;
  }
  return W;
}

constexpr W3 W_00 = wig(0,0,0);
constexpr W3 W_01 = wig(0,1,1);
constexpr W3 W_02 = wig(0,2,2);
constexpr W3 W_03 = wig(1,0,1);
constexpr W3 W_04 = wig(1,1,0);
constexpr W3 W_05 = wig(1,1,1);
constexpr W3 W_06 = wig(1,1,2);
constexpr W3 W_07 = wig(1,2,1);
constexpr W3 W_08 = wig(1,2,2);
constexpr W3 W_09 = wig(2,0,2);
constexpr W3 W_10 = wig(2,1,1);
constexpr W3 W_11 = wig(2,1,2);
constexpr W3 W_12 = wig(2,2,0);
constexpr W3 W_13 = wig(2,2,1);
constexpr W3 W_14 = wig(2,2,2);

struct Entry { int p, gi, gj, gk; float v; };
struct Table { Entry e[615]; int n; };
constexpr Table build(){
  const W3 WS[NP] = { W_00,W_01,W_02,W_03,W_04,W_05,W_06,W_07,
                      W_08,W_09,W_10,W_11,W_12,W_13,W_14 };
  Table t{};
  for (int p = 0; p < NP; ++p){
    const int l1 = P1[p], l2 = P2[p], l3 = P3[p];
    for (int i = 0; i < 2*l1+1; ++i)
      for (int j = 0; j < 2*l2+1; ++j)
        for (int k = 0; k < 2*l3+1; ++k){
          double v = WS[p].w[i][j][k];
          if (v > 1e-12 || v < -1e-12){
            t.e[t.n] = Entry{ p, BASE[l1] + i, BASE[l2] + j, BASE[l3] + k, (float)v };
            ++t.n;
          }
        }
  }
  return t;
}
constexpr Table TBL = build();
constexpr int NNZ = TBL.n;

} // namespace w3j

// ---------------------------------------------------------------------------
// Unrolled sparse contraction (all indices/coefficients compile-time const).
// ---------------------------------------------------------------------------
template<int E>
__device__ __forceinline__ void apply_one(const float (&xx)[9], const float (&yv)[9],
                                          const float (&wp)[w3j::NP], float (&oo)[9]){
  constexpr w3j::Entry en = w3j::TBL.e[E];
  oo[en.gk] = fmaf(wp[en.p] * xx[en.gi] * en.v, yv[en.gj], oo[en.gk]);
}

template<int... Es>
__device__ __forceinline__ void apply_all(std::integer_sequence<int, Es...>,
                                          const float (&xx)[9], const float (&yv)[9],
                                          const float (&wp)[w3j::NP], float (&oo)[9]){
  (apply_one<Es>(xx, yv, wp, oo), ...);
}

// ---------------------------------------------------------------------------
// R3 structure (barrier-free wave-private LDS staging) + NON-TEMPORAL global
// load/store. The 604 MB read+write streams have zero reuse -> bypass L2
// allocation (nt flag) to kill write-allocate pressure / dirty-eviction
// serialization in the 32 MB L2.
//   NOTE: __builtin_nontemporal_* requires clang-native vector types, so the
//   staging copies use ext_vector_type(4) float (16 B aligned), not float4.
// ---------------------------------------------------------------------------
typedef float v4f __attribute__((ext_vector_type(4)));   // 16 B aligned

constexpr int WROWS = 4;                    // rows per wave
constexpr int ROWS  = 16;                   // rows per block (4 waves)
constexpr int RF    = 576;                  // floats per row
constexpr int WF    = WROWS * RF;           // 2304 floats per wave region
constexpr int WV4   = WF / 4 / 64;          // v4f per lane = 9

__global__ __launch_bounds__(256)
void tp_rescale_kernel(const float* __restrict__ x, const float* __restrict__ y,
                       const float* __restrict__ w, const float* __restrict__ b,
                       float* __restrict__ out)
{
  __shared__ float lds[ROWS * RF];          // 36864 B

  const int t    = threadIdx.x;
  const int lane = t & 63;
  const int wv   = __builtin_amdgcn_readfirstlane(t >> 6);   // SGPR wave id
  const long rowbase = (long)blockIdx.x * ROWS + wv * WROWS; // first row of wave

  float* wlds = lds + wv * WF;              // wave-private region (no restrict!)

  // ---- stage-in: nontemporal v4f copy global -> LDS ----
  {
    const v4f* __restrict__ src = (const v4f*)(x + rowbase * RF);
    v4f* dst = (v4f*)wlds;
    #pragma unroll
    for (int i = 0; i < WV4; ++i)
      dst[i * 64 + lane] = __builtin_nontemporal_load(&src[i * 64 + lane]);
  }
  asm volatile("" ::: "memory");            // compiler fence (no instruction)

  // ---- per-lane weights/bias (L1-resident broadcast reads) ----
  const int u = lane;
  float wp[w3j::NP];
  #pragma unroll
  for (int p = 0; p < w3j::NP; ++p) wp[p] = w[p * 64 + u];
  const float bu = b[u];

  // ---- compute: 4 rows, outputs written back in place (wave-local order) ----
  #pragma unroll
  for (int r = 0; r < WROWS; ++r) {
    float* xr = wlds + r * RF;              // no restrict
    const float* yr = y + (rowbase + r) * 9;  // wave-uniform addr -> s_load

    float xx[9], yv[9], oo[9];
    xx[0] = xr[u];
    #pragma unroll
    for (int i = 0; i < 3; ++i) xx[1 + i] = xr[64 + 3 * u + i];
    #pragma unroll
    for (int k = 0; k < 5; ++k) xx[4 + k] = xr[256 + 5 * u + k];
    #pragma unroll
    for (int j = 0; j < 9; ++j) yv[j] = yr[j];
    #pragma unroll
    for (int k = 0; k < 9; ++k) oo[k] = 0.0f;

    apply_all(std::make_integer_sequence<int, w3j::NNZ>{}, xx, yv, wp, oo);

    // in-place write-back: row r inputs already in regs; same-wave DS pipe
    // is program-ordered, so stage-out reads below see these values.
    xr[u] = oo[0] + bu;                      // bias only on the 0e slice
    #pragma unroll
    for (int i = 0; i < 3; ++i) xr[64 + 3 * u + i] = oo[1 + i];
    #pragma unroll
    for (int k = 0; k < 5; ++k) xr[256 + 5 * u + k] = oo[4 + k];
  }
  asm volatile("" ::: "memory");            // compiler fence (no instruction)

  // ---- stage-out: nontemporal v4f copy LDS -> global ----
  {
    const v4f* src = (const v4f*)wlds;
    v4f* __restrict__ dst = (v4f*)(out + rowbase * RF);
    #pragma unroll
    for (int i = 0; i < WV4; ++i)
      __builtin_nontemporal_store(src[i * 64 + lane], &dst[i * 64 + lane]);
  }
}

extern "C" void kernel_launch(void* const* d_in, const int* in_sizes, int n_in,
                              void* d_out, int out_size, void* d_ws, size_t ws_size,
                              hipStream_t stream) {
  const float* x = (const float*)d_in[0];
  const float* y = (const float*)d_in[1];
  const float* w = (const float*)d_in[2];
  const float* b = (const float*)d_in[3];
  float* out = (float*)d_out;

  const int nrows = in_sizes[0] / 576;      // 131072, divisible by ROWS=16
  const int blocks = nrows / ROWS;          // 8192

  hipLaunchKernelGGL(tp_rescale_kernel, dim3(blocks), dim3(256), 0, stream,
                     x, y, w, b, out);
}